// Round 23
// baseline (150.156 us; speedup 1.0000x reference)
//
#include <hip/hip_runtime.h>
#include <stdint.h>

// ---------------- types & helpers ----------------
typedef short sh4 __attribute__((ext_vector_type(4)));
typedef short short8 __attribute__((ext_vector_type(8)));
typedef float f32x4 __attribute__((ext_vector_type(4)));
typedef float f4 __attribute__((ext_vector_type(4)));
typedef _Float16 half4 __attribute__((ext_vector_type(4)));
typedef _Float16 half8 __attribute__((ext_vector_type(8)));
typedef unsigned int uint2v __attribute__((ext_vector_type(2)));

__device__ __forceinline__ short f2h(float f) {
    _Float16 h = (_Float16)f;
    return __builtin_bit_cast(short, h);
}

__device__ __forceinline__ f32x4 mfma_k32(short8 a, short8 b, f32x4 c) {
    return __builtin_amdgcn_mfma_f32_16x16x32_f16(
        __builtin_bit_cast(half8, a), __builtin_bit_cast(half8, b), c, 0, 0, 0);
}
__device__ __forceinline__ f32x4 mfma_k16(half4 a, half4 b, f32x4 c) {
    return __builtin_amdgcn_mfma_f32_16x16x16f16(a, b, c, 0, 0, 0);
}
__device__ __forceinline__ unsigned int pkrtz(float a, float b) {
    return __builtin_bit_cast(unsigned int, __builtin_amdgcn_cvt_pkrtz(a, b));
}
__device__ __forceinline__ float exp2_raw(float x) {
    float r;
    asm("v_exp_f32 %0, %1" : "=v"(r) : "v"(x));   // 2^x, single instr
    return r;
}

// Problem constants: B=4, C=256, H=W=128 (PX=16384), inner=256, heads=8, c/head=32,
// patch=8 -> keys=256, conv K-dim = 256*64 = 16384.
// NOTE (r6/r14): exp shift must be the exact row max from the logits.
// NOTE (r9-r11): f16 logit stash -> wrong results (bisected). f32 stash is FINE.
// NOTE (r9 vs r10): ones-row MFMA denominator == shfl-sum; verified since r16.
// NOTE (r16): q is PRE-SCALED by log2(e) in the q-gemm -> raw v_exp_f32 in attn.
// NOTE (r17/r20): k_attn LDS bank-conflict counter is structural; ~83% issue-bound.
// NOTE (r21): LDS-free kv_gemm = 6x regression (latency-bound). Keep LDS staging.
// NOTE (r23): kernel fusion (7 -> 4 dispatches): pack_x|pack_w|pack_wq merged;
//   kv_gemm|q_gemm merged (bid%3 interleave, shared 32KB LDS union). No index
//   or arithmetic changes inside any body — pure dispatch restructure.

// ---------------- pack bodies ----------------
__device__ __forceinline__ void transpose64(const float* __restrict__ src,
                                            short* __restrict__ dst,
                                            int srcSlowStride, int dstRowStride,
                                            float (*tile)[65]) {
    const int t = threadIdx.x;
#pragma unroll
    for (int i = 0; i < 4; ++i) {
        int idx = i * 1024 + t * 4;
        int fast = idx & 63, slow = idx >> 6;
        f4 v = *(const f4*)(src + (long)slow * srcSlowStride + fast);
        tile[slow][fast]     = v[0];
        tile[slow][fast + 1] = v[1];
        tile[slow][fast + 2] = v[2];
        tile[slow][fast + 3] = v[3];
    }
    __syncthreads();
#pragma unroll
    for (int i = 0; i < 2; ++i) {
        int ch = i * 256 + t;
        int fast = ch >> 3, sg = ch & 7;
        short8 v;
#pragma unroll
        for (int j = 0; j < 8; ++j) v[j] = f2h(tile[sg * 8 + j][fast]);
        *(short8*)(dst + (long)fast * dstRowStride + sg * 8) = v;
    }
}

// fused packs: grid 6400 = 4096 pack_x | 2048 pack_w | 256 pack_wq
__global__ __launch_bounds__(256) void k_pack_all(const float* __restrict__ x,
                                                  const float* __restrict__ wk,
                                                  const float* __restrict__ wv,
                                                  const float* __restrict__ wq,
                                                  short* __restrict__ xn,
                                                  short* __restrict__ wp,
                                                  short* __restrict__ wqp) {
    __shared__ float tile[64][65];
    int bid = blockIdx.x;
    if (bid < 4096) {
        // x: [4][256][16384] fp32 (NCHW) -> xn: [4][16384][256] f16 (NHWC)
        int bi = bid;                        // 4096 = 4b * 256pxt * 4ct
        int ct = bi & 3, pxt = (bi >> 2) & 255, b = bi >> 10;
        const float* src = x + (((long)(b * 256 + ct * 64)) << 14) + (long)pxt * 64;
        short* dst = xn + (((long)(b << 14) + pxt * 64) * 256) + ct * 64;
        transpose64(src, dst, 16384, 256, tile);
    } else if (bid < 6144) {
        // Wk/Wv -> wp: [512][64][256] f16 (oc<256: k, else v), K order (dydx, c)
        int bi = bid - 4096;                 // 2048 = 512oc * 4ct
        int ct = bi & 3, oc = bi >> 2;
        const float* base = (oc < 256) ? (wk + (long)oc * 16384)
                                       : (wv + (long)(oc - 256) * 16384);
        const float* src = base + ct * 4096; // + c0*64
        short* dst = wp + (long)oc * 16384 + ct * 64;
        transpose64(src, dst, 64, 256, tile);
    } else {
        // Wq: [256][256] fp32 -> f16 (layout preserved)
        int i = (bid - 6144) * 256 + threadIdx.x;
        wqp[i] = f2h(wq[i]);
    }
}

// ---------------- fused GEMMs: kv conv + q conv ----------------
// grid 1536, bid%3==2 -> kv block (512 of them), else q block (1024).
// Shared 32KB LDS union: kv uses 24KB (Al 16K + Bl 8K), q uses 32KB (Tb).

__device__ __forceinline__ void kv_gemm_body(const short* __restrict__ xn,
                                             const short* __restrict__ wp,
                                             float* __restrict__ part,
                                             int bid, short* smem) {
    short* Al = smem;          // 128*64 shorts, rows 128B = 8 granules, swizzled
    short* Bl = smem + 8192;   // 64*64 shorts
    int wg = (bid & 7) * 64 + (bid >> 3);       // swizzle (512 = 8*64)
    int nb = wg & 7, pm = (wg >> 3) & 7, kc = wg >> 6;
    int t = threadIdx.x, l = t & 63, w = t >> 6;
    int wm = w >> 1, wn = w & 1;
    int low = l & 15, q = l >> 4;

    short* lda[4];
    short* ldb[2];
#pragma unroll
    for (int i = 0; i < 4; ++i) {
        int g = i * 256 + t;
        int row = g >> 3, lg = g & 7;
        lda[i] = Al + row * 64 + ((lg ^ (row & 7)) * 8);
    }
#pragma unroll
    for (int i = 0; i < 2; ++i) {
        int g = i * 256 + t;
        int row = g >> 3, lg = g & 7;
        ldb[i] = Bl + row * 64 + ((lg ^ (row & 7)) * 8);
    }

    f32x4 acc[4][2];
#pragma unroll
    for (int mt = 0; mt < 4; ++mt)
#pragma unroll
        for (int nt = 0; nt < 2; ++nt) acc[mt][nt] = (f32x4){0.f, 0.f, 0.f, 0.f};

#pragma unroll 1
    for (int kk4 = 0; kk4 < 8; ++kk4) {
        const short* apt[4];
        const short* bpt[2];
        int dydx = kc * 8 + kk4;
#pragma unroll
        for (int i = 0; i < 4; ++i) {
            int g = i * 256 + t;
            int row = g >> 3, lg = g & 7;
            int patch = pm * 128 + row;
            int bb = patch >> 8, pid = patch & 255;
            int ph = pid >> 4, pw = pid & 15;
            int px = (ph * 8 + (dydx >> 3)) * 128 + pw * 8 + (dydx & 7);
            apt[i] = xn + ((long)(bb << 14) + px) * 256 + lg * 8;
        }
#pragma unroll
        for (int i = 0; i < 2; ++i) {
            int g = i * 256 + t;
            int row = g >> 3, lg = g & 7;
            int oc = nb * 64 + row;
            bpt[i] = wp + (long)oc * 16384 + kc * 2048 + kk4 * 256 + lg * 8;
        }
#pragma unroll
        for (int j = 0; j < 4; ++j) {
            short8 va[4], vb[2];
#pragma unroll
            for (int i = 0; i < 4; ++i) va[i] = *(const short8*)(apt[i] + j * 64);
#pragma unroll
            for (int i = 0; i < 2; ++i) vb[i] = *(const short8*)(bpt[i] + j * 64);
#pragma unroll
            for (int i = 0; i < 4; ++i) *(short8*)lda[i] = va[i];
#pragma unroll
            for (int i = 0; i < 2; ++i) *(short8*)ldb[i] = vb[i];
            __syncthreads();
#pragma unroll
            for (int ks = 0; ks < 2; ++ks) {
                short8 af[4], bf[2];
#pragma unroll
                for (int mt = 0; mt < 4; ++mt) {
                    int row = wm * 64 + mt * 16 + low;
                    int lg = ks * 4 + q;
                    af[mt] = *(const short8*)(Al + row * 64 + ((lg ^ (row & 7)) * 8));
                }
#pragma unroll
                for (int nt = 0; nt < 2; ++nt) {
                    int row = wn * 32 + nt * 16 + low;
                    int lg = ks * 4 + q;
                    bf[nt] = *(const short8*)(Bl + row * 64 + ((lg ^ (row & 7)) * 8));
                }
#pragma unroll
                for (int mt = 0; mt < 4; ++mt)
#pragma unroll
                    for (int nt = 0; nt < 2; ++nt)
                        acc[mt][nt] = mfma_k32(af[mt], bf[nt], acc[mt][nt]);
            }
            __syncthreads();
        }
    }
#pragma unroll
    for (int mt = 0; mt < 4; ++mt) {
        int patch = pm * 128 + wm * 64 + mt * 16 + q * 4;
#pragma unroll
        for (int nt = 0; nt < 2; ++nt) {
            int oc = nb * 64 + wn * 32 + nt * 16 + low;
#pragma unroll
            for (int r = 0; r < 4; ++r)
                part[((long)kc * 1024 + patch + r) * 512 + oc] = acc[mt][nt][r];
        }
    }
}

__device__ __forceinline__ void q_gemm_body(const short* __restrict__ xn,
                                            const short* __restrict__ wqp,
                                            const float* __restrict__ bq,
                                            short* __restrict__ qp,
                                            int bi, short* smem) {
    short* Tb = smem;               // 64*256 shorts = 32KB
    int b = bi >> 8, tile = bi & 255;
    long px0 = (long)tile * 64;
    int t = threadIdx.x, l = t & 63, w = t >> 6;
    int low = l & 15, q = l >> 4;

    const short* xb = xn + (((long)(b << 14)) + px0) * 256;

    float bqv[4];
#pragma unroll
    for (int nt = 0; nt < 4; ++nt) bqv[nt] = bq[w * 64 + nt * 16 + low];

    f32x4 acc[4][4];   // [mt: px][nt: oc]
#pragma unroll
    for (int mt = 0; mt < 4; ++mt)
#pragma unroll
        for (int nt = 0; nt < 4; ++nt) acc[mt][nt] = (f32x4){0.f, 0.f, 0.f, 0.f};

#pragma unroll
    for (int kstep = 0; kstep < 8; ++kstep) {
        short8 af[4], bf[4];
#pragma unroll
        for (int mt = 0; mt < 4; ++mt)
            af[mt] = *(const short8*)(xb + (mt * 16 + low) * 256 + kstep * 32 + q * 8);
#pragma unroll
        for (int nt = 0; nt < 4; ++nt)
            bf[nt] = *(const short8*)(wqp + (w * 64 + nt * 16 + low) * 256 + kstep * 32 + q * 8);
#pragma unroll
        for (int mt = 0; mt < 4; ++mt)
#pragma unroll
            for (int nt = 0; nt < 4; ++nt)
                acc[mt][nt] = mfma_k32(af[mt], bf[nt], acc[mt][nt]);
    }
    // D: px = mt*16 + q*4 + r, oc = w*64 + nt*16 + low.
    // Tb[px][h 8][c 32] pitch 256 shorts; 16B-granule index XOR (px&7).
    const float LOG2E = 1.44269504088896f;
#pragma unroll
    for (int mt = 0; mt < 4; ++mt)
#pragma unroll
        for (int nt = 0; nt < 4; ++nt) {
            int oc = w * 64 + nt * 16 + low;
            int h8 = oc & 7, cc = oc >> 3;
            int gi = h8 * 4 + (cc >> 3);          // 16B granule 0..31 within row
#pragma unroll
            for (int r = 0; r < 4; ++r) {
                int px = mt * 16 + q * 4 + r;
                Tb[px * 256 + ((gi ^ (px & 7)) * 8) + (cc & 7)] =
                    f2h((acc[mt][nt][r] + bqv[nt]) * LOG2E);
            }
        }
    __syncthreads();
#pragma unroll
    for (int i = 0; i < 8; ++i) {
        int g = i * 256 + t;            // 2048 chunks of 16B
        int pxl = g >> 5, g16 = g & 31; // g16 = hh*4 + oct
        int hh = g16 >> 2, oct = g16 & 3;
        short8 v = *(const short8*)(Tb + pxl * 256 + ((g16 ^ (pxl & 7)) * 8));
        *(short8*)(qp + (((long)(b * 8 + hh) * 16384) + px0 + pxl) * 32 + oct * 8) = v;
    }
}

__global__ __launch_bounds__(256) void k_gemm_all(const short* __restrict__ xn,
                                                  const short* __restrict__ wp,
                                                  const short* __restrict__ wqp,
                                                  const float* __restrict__ bq,
                                                  float* __restrict__ part,
                                                  short* __restrict__ qp) {
    __shared__ __attribute__((aligned(16))) short smem[16384];  // 32KB union
    int bid = blockIdx.x;                 // 1536
    int k3 = bid / 3, r3 = bid - k3 * 3;
    if (r3 == 2) kv_gemm_body(xn, wp, part, k3, smem);          // 512 blocks
    else         q_gemm_body(xn, wqp, bq, qp, k3 * 2 + r3, smem); // 1024 blocks
}

// reduce partials, add bias, pack k -> [b][h][key][c], v -> [b][h][c][key] (f16)
__global__ __launch_bounds__(256) void k_kv_fin(const float* __restrict__ part,
                                                const float* __restrict__ bk,
                                                const float* __restrict__ bv,
                                                short* __restrict__ kp,
                                                short* __restrict__ vp) {
    int idx = blockIdx.x * 256 + threadIdx.x;   // 524288 = 1024patch * 512oc
    int oc = idx & 511, patch = idx >> 9;
    float s = 0.f;
#pragma unroll
    for (int kc = 0; kc < 8; ++kc) s += part[(long)kc * 524288 + idx];
    int b = patch >> 8, key = patch & 255;
    if (oc < 256) {
        s += bk[oc];
        kp[(((long)(b * 8 + (oc & 7)) * 256) + key) * 32 + (oc >> 3)] = f2h(s);
    } else {
        int o = oc - 256;
        s += bv[o];
        vp[(((long)(b * 8 + (o & 7)) * 32) + (o >> 3)) * 256 + key] = f2h(s);
    }
}

// ---------------- fused attention (v15: K in registers, V-only LDS) ----
// grid 2048 = 4b * 8h * 64 tiles of 256px; block 256 thr = 4 waves x 64 px.
// kf[16] registers (loaded once, L2-hot); single-pass QK^T with f32 dd[16]
// stash; exp2 on f32 outputs; ones-row MFMA denominator; setprio around PV.
__global__ __launch_bounds__(256) void k_attn(const short* __restrict__ qp,
                                              const short* __restrict__ kp,
                                              const short* __restrict__ vp,
                                              float* __restrict__ out) {
    __shared__ short Vl[32 * 264];   // 16.9 KB (V only)
    int bi = blockIdx.x;
    int tile = bi & 63, h = (bi >> 6) & 7, b = bi >> 9;
    int bh = b * 8 + h;
    long px0 = (long)tile * 256;
    int t = threadIdx.x, l = t & 63, w = t >> 6;
    int low = l & 15, q = l >> 4;

    const short* kbase = kp + (long)bh * 8192;    // [key 256][c 32]
    const short* vbase = vp + (long)bh * 8192;    // [c 32][key 256]
    const short* qbase = qp + (long)bh * 16384 * 32;  // [px][c 32]

    // stage V -> LDS (pitch 264)
#pragma unroll
    for (int i = 0; i < 4; ++i) {
        int g = i * 256 + t;
        int c = g >> 5, k8 = g & 31;
        *(short8*)(Vl + c * 264 + k8 * 8) = *(const short8*)(vbase + c * 256 + k8 * 8);
    }
    // K fragments -> registers (loaded once, reused by all 4 nt; L2-hot tile)
    short8 kf[16];
#pragma unroll
    for (int mt = 0; mt < 16; ++mt)
        kf[mt] = *(const short8*)(kbase + (mt * 16 + low) * 32 + q * 8);
    __syncthreads();

    const short* vA = Vl + low * 264 + q * 4;  // + ct*4224 + kc*16 (imm offset)
    const sh4 sone = {0x3C00, 0x3C00, 0x3C00, 0x3C00};
    const half4 vones = __builtin_bit_cast(half4, sone);

#pragma unroll 1
    for (int nt = 0; nt < 4; ++nt) {
        long px = px0 + w * 64 + nt * 16 + low;
        // q B-frag: 16B contiguous (k = c = q*8+j); values log2e-scaled
        short8 bq2 = *(const short8*)(qbase + px * 32 + q * 8);

        // single QK^T pass: f32 stash + folded row max (r5/r18-verified)
        f32x4 dd[16];
        float m = -1e30f;
#pragma unroll
        for (int mt = 0; mt < 16; ++mt) {
            dd[mt] = mfma_k32(kf[mt], bq2, (f32x4){0.f, 0.f, 0.f, 0.f});
            m = fmaxf(fmaxf(dd[mt][0], dd[mt][1]), m);
            m = fmaxf(fmaxf(dd[mt][2], dd[mt][3]), m);
        }
        m = fmaxf(m, __shfl_xor(m, 16));
        m = fmaxf(m, __shfl_xor(m, 32));

        // exp2 from f32 stash, pack P to f16
        uint2v pk[16];
#pragma unroll
        for (int mt = 0; mt < 16; ++mt) {
            float p0 = exp2_raw(dd[mt][0] - m);
            float p1 = exp2_raw(dd[mt][1] - m);
            float p2 = exp2_raw(dd[mt][2] - m);
            float p3 = exp2_raw(dd[mt][3] - m);
            pk[mt][0] = pkrtz(p0, p1);
            pk[mt][1] = pkrtz(p2, p3);
        }

        // PV + ones-row denominator (both on the MFMA pipe)
        f32x4 o2[2], os;
        o2[0] = (f32x4){0.f, 0.f, 0.f, 0.f};
        o2[1] = (f32x4){0.f, 0.f, 0.f, 0.f};
        os    = (f32x4){0.f, 0.f, 0.f, 0.f};
        __builtin_amdgcn_s_setprio(1);
#pragma unroll
        for (int kc = 0; kc < 16; ++kc) {
            half4 pb = __builtin_bit_cast(half4, pk[kc]);
            half4 av0 = __builtin_bit_cast(half4, *(const sh4*)(vA + kc * 16));
            half4 av1 = __builtin_bit_cast(half4, *(const sh4*)(vA + 4224 + kc * 16));
            o2[0] = mfma_k16(av0, pb, o2[0]);
            o2[1] = mfma_k16(av1, pb, o2[1]);
            os    = mfma_k16(vones, pb, os);
        }
        __builtin_amdgcn_s_setprio(0);
        float inv = 1.0f / os[0];   // column sum for this lane's px

        // write out [b][c*8+h][px] fp32; D row=c=ct*16+q*4+r, col=px
#pragma unroll
        for (int ct = 0; ct < 2; ++ct)
#pragma unroll
            for (int r = 0; r < 4; ++r) {
                int c = ct * 16 + q * 4 + r;
                out[(((long)(b * 256 + c * 8 + h)) << 14) + px] = o2[ct][r] * inv;
            }
    }
}

// ---------------- launch ----------------
extern "C" void kernel_launch(void* const* d_in, const int* in_sizes, int n_in,
                              void* d_out, int out_size, void* d_ws, size_t ws_size,
                              hipStream_t stream) {
    const float* x  = (const float*)d_in[0];
    const float* Wq = (const float*)d_in[1];
    const float* bq = (const float*)d_in[2];
    const float* Wk = (const float*)d_in[3];
    const float* bk = (const float*)d_in[4];
    const float* Wv = (const float*)d_in[5];
    const float* bv = (const float*)d_in[6];
    float* out = (float*)d_out;

    char* ws = (char*)d_ws;
    const size_t OFF_XN = 0;             // 33,554,432  x NHWC f16
    const size_t OFF_Q  = 33554432;      // 33,554,432  q [b][h][px][c] f16 (log2e-scaled)
    const size_t OFF_WP = 67108864;      // 16,777,216  w_pack [512][16384] f16
    const size_t OFF_WQ = 83886080;      //    131,072  wq f16
    const size_t OFF_KP = 84017152;      //    524,288  k_pack f16
    const size_t OFF_VP = 84541440;      //    524,288  v_pack f16
    const size_t OFF_PT = 85065728;      // 16,777,216  partials fp32 [8][1024][512]
    const size_t NEEDED = 118620160;
    if (ws_size < NEEDED) return;        // fail loudly via validation

    short* xn  = (short*)(ws + OFF_XN);
    short* qp  = (short*)(ws + OFF_Q);
    short* wp  = (short*)(ws + OFF_WP);
    short* wqp = (short*)(ws + OFF_WQ);
    short* kp  = (short*)(ws + OFF_KP);
    short* vp  = (short*)(ws + OFF_VP);
    float* part= (float*)(ws + OFF_PT);

    k_pack_all<<<dim3(6400), dim3(256), 0, stream>>>(x, Wk, Wv, Wq, xn, wp, wqp);
    k_gemm_all<<<dim3(1536), dim3(256), 0, stream>>>(xn, wp, wqp, bq, part, qp);
    k_kv_fin  <<<dim3(2048), dim3(256), 0, stream>>>(part, bk, bv, kp, vp);
    k_attn    <<<dim3(2048), dim3(256), 0, stream>>>(qp, kp, vp, out);
}

// Round 24
// 141.999 us; speedup vs baseline: 1.0574x; 1.0574x over previous
//
#include <hip/hip_runtime.h>
#include <stdint.h>

// ---------------- types & helpers ----------------
typedef short sh4 __attribute__((ext_vector_type(4)));
typedef short short8 __attribute__((ext_vector_type(8)));
typedef float f32x4 __attribute__((ext_vector_type(4)));
typedef float f4 __attribute__((ext_vector_type(4)));
typedef _Float16 half4 __attribute__((ext_vector_type(4)));
typedef _Float16 half8 __attribute__((ext_vector_type(8)));
typedef unsigned int uint2v __attribute__((ext_vector_type(2)));

__device__ __forceinline__ short f2h(float f) {
    _Float16 h = (_Float16)f;
    return __builtin_bit_cast(short, h);
}

__device__ __forceinline__ f32x4 mfma_k32(short8 a, short8 b, f32x4 c) {
    return __builtin_amdgcn_mfma_f32_16x16x32_f16(
        __builtin_bit_cast(half8, a), __builtin_bit_cast(half8, b), c, 0, 0, 0);
}
__device__ __forceinline__ f32x4 mfma_k16(half4 a, half4 b, f32x4 c) {
    return __builtin_amdgcn_mfma_f32_16x16x16f16(a, b, c, 0, 0, 0);
}
__device__ __forceinline__ unsigned int pkrtz(float a, float b) {
    return __builtin_bit_cast(unsigned int, __builtin_amdgcn_cvt_pkrtz(a, b));
}
__device__ __forceinline__ float exp2_raw(float x) {
    float r;
    asm("v_exp_f32 %0, %1" : "=v"(r) : "v"(x));   // 2^x, single instr
    return r;
}

// Problem constants: B=4, C=256, H=W=128 (PX=16384), inner=256, heads=8, c/head=32,
// patch=8 -> keys=256, conv K-dim = 256*64 = 16384.
// NOTE (r6/r14): exp shift must be the exact row max from the logits.
// NOTE (r9-r11): f16 logit stash -> wrong results (bisected). f32 stash is FINE.
// NOTE (r9 vs r10): ones-row MFMA denominator == shfl-sum; verified since r16.
// NOTE (r16): q is PRE-SCALED by log2(e) in the q-gemm -> raw v_exp_f32 in attn.
// NOTE (r17/r20): k_attn LDS bank-conflict counter is structural; ~83% issue-bound.
// NOTE (r21): LDS-free kv_gemm = 6x regression (latency-bound). Keep LDS staging.
// NOTE (r23): GEMM fusion (-12us penalty: LDS-union occupancy + interleave broke
//   XCD swizzle) -> un-fused. Pack fusion kept (~20us, fine). Counters showed
//   kv+q gemms ~67us combined, kv occupancy GRID-limited (512 = 2 blocks/CU)
//   -> r24 splits pm 8->16 (grid 1024, 4 blocks/CU, 16KB LDS).

// ---------------- pack bodies ----------------
__device__ __forceinline__ void transpose64(const float* __restrict__ src,
                                            short* __restrict__ dst,
                                            int srcSlowStride, int dstRowStride,
                                            float (*tile)[65]) {
    const int t = threadIdx.x;
#pragma unroll
    for (int i = 0; i < 4; ++i) {
        int idx = i * 1024 + t * 4;
        int fast = idx & 63, slow = idx >> 6;
        f4 v = *(const f4*)(src + (long)slow * srcSlowStride + fast);
        tile[slow][fast]     = v[0];
        tile[slow][fast + 1] = v[1];
        tile[slow][fast + 2] = v[2];
        tile[slow][fast + 3] = v[3];
    }
    __syncthreads();
#pragma unroll
    for (int i = 0; i < 2; ++i) {
        int ch = i * 256 + t;
        int fast = ch >> 3, sg = ch & 7;
        short8 v;
#pragma unroll
        for (int j = 0; j < 8; ++j) v[j] = f2h(tile[sg * 8 + j][fast]);
        *(short8*)(dst + (long)fast * dstRowStride + sg * 8) = v;
    }
}

// fused packs: grid 6400 = 4096 pack_x | 2048 pack_w | 256 pack_wq
__global__ __launch_bounds__(256) void k_pack_all(const float* __restrict__ x,
                                                  const float* __restrict__ wk,
                                                  const float* __restrict__ wv,
                                                  const float* __restrict__ wq,
                                                  short* __restrict__ xn,
                                                  short* __restrict__ wp,
                                                  short* __restrict__ wqp) {
    __shared__ float tile[64][65];
    int bid = blockIdx.x;
    if (bid < 4096) {
        // x: [4][256][16384] fp32 (NCHW) -> xn: [4][16384][256] f16 (NHWC)
        int bi = bid;                        // 4096 = 4b * 256pxt * 4ct
        int ct = bi & 3, pxt = (bi >> 2) & 255, b = bi >> 10;
        const float* src = x + (((long)(b * 256 + ct * 64)) << 14) + (long)pxt * 64;
        short* dst = xn + (((long)(b << 14) + pxt * 64) * 256) + ct * 64;
        transpose64(src, dst, 16384, 256, tile);
    } else if (bid < 6144) {
        // Wk/Wv -> wp: [512][64][256] f16 (oc<256: k, else v), K order (dydx, c)
        int bi = bid - 4096;                 // 2048 = 512oc * 4ct
        int ct = bi & 3, oc = bi >> 2;
        const float* base = (oc < 256) ? (wk + (long)oc * 16384)
                                       : (wv + (long)(oc - 256) * 16384);
        const float* src = base + ct * 4096; // + c0*64
        short* dst = wp + (long)oc * 16384 + ct * 64;
        transpose64(src, dst, 64, 256, tile);
    } else {
        // Wq: [256][256] fp32 -> f16 (layout preserved)
        int i = (bid - 6144) * 256 + threadIdx.x;
        wqp[i] = f2h(wq[i]);
    }
}

// ---------------- K/V conv as GEMM (v6: 64x64 tile, grid 1024, 4/CU) ----
// C[patch 1024][oc 512] = A[patch][k 16384] * B[k][oc]
// grid 1024 = 8kc * 16pm * 8nb; block 256 thr (4 waves); Kchunk 2048.
// kk-loop: 8 outer kk4 (addresses hoisted) x 4 unrolled j (imm offsets).
__global__ __launch_bounds__(256) void k_kv_gemm(const short* __restrict__ xn,
                                                 const short* __restrict__ wp,
                                                 float* __restrict__ part) {
    __shared__ short Al[64 * 64]; // rows 128B = 8 granules, swizzled
    __shared__ short Bl[64 * 64];
    int bid = blockIdx.x;                       // 1024
    int wg = (bid & 7) * 128 + (bid >> 3);      // XCD-contiguous swizzle (1024 = 8*128)
    int nb = wg & 7, pm = (wg >> 3) & 15, kc = wg >> 7;
    int t = threadIdx.x, l = t & 63, w = t >> 6;
    int wm = w >> 1, wn = w & 1;
    int low = l & 15, q = l >> 4;

    // LDS staging addresses (loop-invariant); each stages 512 granules
    short* lda[2];
    short* ldb[2];
#pragma unroll
    for (int i = 0; i < 2; ++i) {
        int g = i * 256 + t;
        int row = g >> 3, lg = g & 7;
        lda[i] = Al + row * 64 + ((lg ^ (row & 7)) * 8);
        ldb[i] = Bl + row * 64 + ((lg ^ (row & 7)) * 8);
    }

    f32x4 acc[2][2];
#pragma unroll
    for (int mt = 0; mt < 2; ++mt)
#pragma unroll
        for (int nt = 0; nt < 2; ++nt) acc[mt][nt] = (f32x4){0.f, 0.f, 0.f, 0.f};

#pragma unroll 1
    for (int kk4 = 0; kk4 < 8; ++kk4) {
        const short* apt[2];
        const short* bpt[2];
        int dydx = kc * 8 + kk4;
#pragma unroll
        for (int i = 0; i < 2; ++i) {
            int g = i * 256 + t;
            int row = g >> 3, lg = g & 7;
            int patch = pm * 64 + row;
            int bb = patch >> 8, pid = patch & 255;
            int ph = pid >> 4, pw = pid & 15;
            int px = (ph * 8 + (dydx >> 3)) * 128 + pw * 8 + (dydx & 7);
            apt[i] = xn + ((long)(bb << 14) + px) * 256 + lg * 8;
        }
#pragma unroll
        for (int i = 0; i < 2; ++i) {
            int g = i * 256 + t;
            int row = g >> 3, lg = g & 7;
            int oc = nb * 64 + row;
            bpt[i] = wp + (long)oc * 16384 + kc * 2048 + kk4 * 256 + lg * 8;
        }
#pragma unroll
        for (int j = 0; j < 4; ++j) {
            short8 va[2], vb[2];
#pragma unroll
            for (int i = 0; i < 2; ++i) va[i] = *(const short8*)(apt[i] + j * 64);
#pragma unroll
            for (int i = 0; i < 2; ++i) vb[i] = *(const short8*)(bpt[i] + j * 64);
#pragma unroll
            for (int i = 0; i < 2; ++i) *(short8*)lda[i] = va[i];
#pragma unroll
            for (int i = 0; i < 2; ++i) *(short8*)ldb[i] = vb[i];
            __syncthreads();
#pragma unroll
            for (int ks = 0; ks < 2; ++ks) {
                short8 af[2], bf[2];
#pragma unroll
                for (int mt = 0; mt < 2; ++mt) {
                    int row = wm * 32 + mt * 16 + low;
                    int lg = ks * 4 + q;
                    af[mt] = *(const short8*)(Al + row * 64 + ((lg ^ (row & 7)) * 8));
                }
#pragma unroll
                for (int nt = 0; nt < 2; ++nt) {
                    int row = wn * 32 + nt * 16 + low;
                    int lg = ks * 4 + q;
                    bf[nt] = *(const short8*)(Bl + row * 64 + ((lg ^ (row & 7)) * 8));
                }
#pragma unroll
                for (int mt = 0; mt < 2; ++mt)
#pragma unroll
                    for (int nt = 0; nt < 2; ++nt)
                        acc[mt][nt] = mfma_k32(af[mt], bf[nt], acc[mt][nt]);
            }
            __syncthreads();
        }
    }
    // D: row(patch) = q*4+r (+16mt+32wm+64pm), col(oc) = low (+16nt+32wn+64nb)
#pragma unroll
    for (int mt = 0; mt < 2; ++mt) {
        int patch = pm * 64 + wm * 32 + mt * 16 + q * 4;
#pragma unroll
        for (int nt = 0; nt < 2; ++nt) {
            int oc = nb * 64 + wn * 32 + nt * 16 + low;
#pragma unroll
            for (int r = 0; r < 4; ++r)
                part[((long)kc * 1024 + patch + r) * 512 + oc] = acc[mt][nt][r];
        }
    }
}

// reduce partials, add bias, pack k -> [b][h][key][c], v -> [b][h][c][key] (f16)
__global__ __launch_bounds__(256) void k_kv_fin(const float* __restrict__ part,
                                                const float* __restrict__ bk,
                                                const float* __restrict__ bv,
                                                short* __restrict__ kp,
                                                short* __restrict__ vp) {
    int idx = blockIdx.x * 256 + threadIdx.x;   // 524288 = 1024patch * 512oc
    int oc = idx & 511, patch = idx >> 9;
    float s = 0.f;
#pragma unroll
    for (int kc = 0; kc < 8; ++kc) s += part[(long)kc * 524288 + idx];
    int b = patch >> 8, key = patch & 255;
    if (oc < 256) {
        s += bk[oc];
        kp[(((long)(b * 8 + (oc & 7)) * 256) + key) * 32 + (oc >> 3)] = f2h(s);
    } else {
        int o = oc - 256;
        s += bv[o];
        vp[(((long)(b * 8 + (o & 7)) * 32) + (o >> 3)) * 256 + key] = f2h(s);
    }
}

// ---------------- Q conv (1x1) as GEMM (no staging LDS, D[px][oc]) -------
// A-frag = xn[px][c], B-frag = wqp[oc][c] (L2-hot). grid 1024; 4 waves.
// q stored as [b][h 8][px 16384][c 32] f16, PRE-SCALED by log2(e) (r16 note).
__global__ __launch_bounds__(256) void k_q_gemm(const short* __restrict__ xn,
                                                const short* __restrict__ wqp,
                                                const float* __restrict__ bq,
                                                short* __restrict__ qp) {
    __shared__ short Tb[64 * 256];  // 32 KB
    int bi = blockIdx.x;            // 1024 = 4b * 256 tiles
    int b = bi >> 8, tile = bi & 255;
    long px0 = (long)tile * 64;
    int t = threadIdx.x, l = t & 63, w = t >> 6;
    int low = l & 15, q = l >> 4;

    const short* xb = xn + (((long)(b << 14)) + px0) * 256;

    float bqv[4];
#pragma unroll
    for (int nt = 0; nt < 4; ++nt) bqv[nt] = bq[w * 64 + nt * 16 + low];

    f32x4 acc[4][4];   // [mt: px][nt: oc]
#pragma unroll
    for (int mt = 0; mt < 4; ++mt)
#pragma unroll
        for (int nt = 0; nt < 4; ++nt) acc[mt][nt] = (f32x4){0.f, 0.f, 0.f, 0.f};

#pragma unroll
    for (int kstep = 0; kstep < 8; ++kstep) {
        short8 af[4], bf[4];
#pragma unroll
        for (int mt = 0; mt < 4; ++mt)
            af[mt] = *(const short8*)(xb + (mt * 16 + low) * 256 + kstep * 32 + q * 8);
#pragma unroll
        for (int nt = 0; nt < 4; ++nt)
            bf[nt] = *(const short8*)(wqp + (w * 64 + nt * 16 + low) * 256 + kstep * 32 + q * 8);
#pragma unroll
        for (int mt = 0; mt < 4; ++mt)
#pragma unroll
            for (int nt = 0; nt < 4; ++nt)
                acc[mt][nt] = mfma_k32(af[mt], bf[nt], acc[mt][nt]);
    }
    // D: px = mt*16 + q*4 + r, oc = w*64 + nt*16 + low.
    // Tb[px][h 8][c 32] pitch 256 shorts; 16B-granule index XOR (px&7).
    const float LOG2E = 1.44269504088896f;
#pragma unroll
    for (int mt = 0; mt < 4; ++mt)
#pragma unroll
        for (int nt = 0; nt < 4; ++nt) {
            int oc = w * 64 + nt * 16 + low;
            int h8 = oc & 7, cc = oc >> 3;
            int gi = h8 * 4 + (cc >> 3);          // 16B granule 0..31 within row
#pragma unroll
            for (int r = 0; r < 4; ++r) {
                int px = mt * 16 + q * 4 + r;
                Tb[px * 256 + ((gi ^ (px & 7)) * 8) + (cc & 7)] =
                    f2h((acc[mt][nt][r] + bqv[nt]) * LOG2E);
            }
        }
    __syncthreads();
#pragma unroll
    for (int i = 0; i < 8; ++i) {
        int g = i * 256 + t;            // 2048 chunks of 16B
        int pxl = g >> 5, g16 = g & 31; // g16 = hh*4 + oct
        int hh = g16 >> 2, oct = g16 & 3;
        short8 v = *(const short8*)(Tb + pxl * 256 + ((g16 ^ (pxl & 7)) * 8));
        *(short8*)(qp + (((long)(b * 8 + hh) * 16384) + px0 + pxl) * 32 + oct * 8) = v;
    }
}

// ---------------- fused attention (v15: K in registers, V-only LDS) ----
// grid 2048 = 4b * 8h * 64 tiles of 256px; block 256 thr = 4 waves x 64 px.
// kf[16] registers (loaded once, L2-hot); single-pass QK^T with f32 dd[16]
// stash; exp2 on f32 outputs; ones-row MFMA denominator; setprio around PV.
__global__ __launch_bounds__(256) void k_attn(const short* __restrict__ qp,
                                              const short* __restrict__ kp,
                                              const short* __restrict__ vp,
                                              float* __restrict__ out) {
    __shared__ short Vl[32 * 264];   // 16.9 KB (V only)
    int bi = blockIdx.x;
    int tile = bi & 63, h = (bi >> 6) & 7, b = bi >> 9;
    int bh = b * 8 + h;
    long px0 = (long)tile * 256;
    int t = threadIdx.x, l = t & 63, w = t >> 6;
    int low = l & 15, q = l >> 4;

    const short* kbase = kp + (long)bh * 8192;    // [key 256][c 32]
    const short* vbase = vp + (long)bh * 8192;    // [c 32][key 256]
    const short* qbase = qp + (long)bh * 16384 * 32;  // [px][c 32]

    // stage V -> LDS (pitch 264)
#pragma unroll
    for (int i = 0; i < 4; ++i) {
        int g = i * 256 + t;
        int c = g >> 5, k8 = g & 31;
        *(short8*)(Vl + c * 264 + k8 * 8) = *(const short8*)(vbase + c * 256 + k8 * 8);
    }
    // K fragments -> registers (loaded once, reused by all 4 nt; L2-hot tile)
    short8 kf[16];
#pragma unroll
    for (int mt = 0; mt < 16; ++mt)
        kf[mt] = *(const short8*)(kbase + (mt * 16 + low) * 32 + q * 8);
    __syncthreads();

    const short* vA = Vl + low * 264 + q * 4;  // + ct*4224 + kc*16 (imm offset)
    const sh4 sone = {0x3C00, 0x3C00, 0x3C00, 0x3C00};
    const half4 vones = __builtin_bit_cast(half4, sone);

#pragma unroll 1
    for (int nt = 0; nt < 4; ++nt) {
        long px = px0 + w * 64 + nt * 16 + low;
        // q B-frag: 16B contiguous (k = c = q*8+j); values log2e-scaled
        short8 bq2 = *(const short8*)(qbase + px * 32 + q * 8);

        // single QK^T pass: f32 stash + folded row max (r5/r18-verified)
        f32x4 dd[16];
        float m = -1e30f;
#pragma unroll
        for (int mt = 0; mt < 16; ++mt) {
            dd[mt] = mfma_k32(kf[mt], bq2, (f32x4){0.f, 0.f, 0.f, 0.f});
            m = fmaxf(fmaxf(dd[mt][0], dd[mt][1]), m);
            m = fmaxf(fmaxf(dd[mt][2], dd[mt][3]), m);
        }
        m = fmaxf(m, __shfl_xor(m, 16));
        m = fmaxf(m, __shfl_xor(m, 32));

        // exp2 from f32 stash, pack P to f16
        uint2v pk[16];
#pragma unroll
        for (int mt = 0; mt < 16; ++mt) {
            float p0 = exp2_raw(dd[mt][0] - m);
            float p1 = exp2_raw(dd[mt][1] - m);
            float p2 = exp2_raw(dd[mt][2] - m);
            float p3 = exp2_raw(dd[mt][3] - m);
            pk[mt][0] = pkrtz(p0, p1);
            pk[mt][1] = pkrtz(p2, p3);
        }

        // PV + ones-row denominator (both on the MFMA pipe)
        f32x4 o2[2], os;
        o2[0] = (f32x4){0.f, 0.f, 0.f, 0.f};
        o2[1] = (f32x4){0.f, 0.f, 0.f, 0.f};
        os    = (f32x4){0.f, 0.f, 0.f, 0.f};
        __builtin_amdgcn_s_setprio(1);
#pragma unroll
        for (int kc = 0; kc < 16; ++kc) {
            half4 pb = __builtin_bit_cast(half4, pk[kc]);
            half4 av0 = __builtin_bit_cast(half4, *(const sh4*)(vA + kc * 16));
            half4 av1 = __builtin_bit_cast(half4, *(const sh4*)(vA + 4224 + kc * 16));
            o2[0] = mfma_k16(av0, pb, o2[0]);
            o2[1] = mfma_k16(av1, pb, o2[1]);
            os    = mfma_k16(vones, pb, os);
        }
        __builtin_amdgcn_s_setprio(0);
        float inv = 1.0f / os[0];   // column sum for this lane's px

        // write out [b][c*8+h][px] fp32; D row=c=ct*16+q*4+r, col=px
#pragma unroll
        for (int ct = 0; ct < 2; ++ct)
#pragma unroll
            for (int r = 0; r < 4; ++r) {
                int c = ct * 16 + q * 4 + r;
                out[(((long)(b * 256 + c * 8 + h)) << 14) + px] = o2[ct][r] * inv;
            }
    }
}

// ---------------- launch ----------------
extern "C" void kernel_launch(void* const* d_in, const int* in_sizes, int n_in,
                              void* d_out, int out_size, void* d_ws, size_t ws_size,
                              hipStream_t stream) {
    const float* x  = (const float*)d_in[0];
    const float* Wq = (const float*)d_in[1];
    const float* bq = (const float*)d_in[2];
    const float* Wk = (const float*)d_in[3];
    const float* bk = (const float*)d_in[4];
    const float* Wv = (const float*)d_in[5];
    const float* bv = (const float*)d_in[6];
    float* out = (float*)d_out;

    char* ws = (char*)d_ws;
    const size_t OFF_XN = 0;             // 33,554,432  x NHWC f16
    const size_t OFF_Q  = 33554432;      // 33,554,432  q [b][h][px][c] f16 (log2e-scaled)
    const size_t OFF_WP = 67108864;      // 16,777,216  w_pack [512][16384] f16
    const size_t OFF_WQ = 83886080;      //    131,072  wq f16
    const size_t OFF_KP = 84017152;      //    524,288  k_pack f16
    const size_t OFF_VP = 84541440;      //    524,288  v_pack f16
    const size_t OFF_PT = 85065728;      // 16,777,216  partials fp32 [8][1024][512]
    const size_t NEEDED = 118620160;
    if (ws_size < NEEDED) return;        // fail loudly via validation

    short* xn  = (short*)(ws + OFF_XN);
    short* qp  = (short*)(ws + OFF_Q);
    short* wp  = (short*)(ws + OFF_WP);
    short* wqp = (short*)(ws + OFF_WQ);
    short* kp  = (short*)(ws + OFF_KP);
    short* vp  = (short*)(ws + OFF_VP);
    float* part= (float*)(ws + OFF_PT);

    k_pack_all<<<dim3(6400), dim3(256), 0, stream>>>(x, Wk, Wv, Wq, xn, wp, wqp);
    k_kv_gemm <<<dim3(1024), dim3(256), 0, stream>>>(xn, wp, part);
    k_kv_fin  <<<dim3(2048), dim3(256), 0, stream>>>(part, bk, bv, kp, vp);
    k_q_gemm  <<<dim3(1024), dim3(256), 0, stream>>>(xn, wqp, bq, qp);
    k_attn    <<<dim3(2048), dim3(256), 0, stream>>>(qp, kp, vp, out);
}